// Round 10
// baseline (751.174 us; speedup 1.0000x reference)
//
#include <hip/hip_runtime.h>

#define SCAN_B 256

typedef __attribute__((ext_vector_type(8))) short bf16x8;
typedef __attribute__((ext_vector_type(4))) float f32x4;

__device__ __forceinline__ ushort f2bf(float f) {
    uint u = __float_as_uint(f);
    uint r = (u + 0x7fffu + ((u >> 16) & 1u)) >> 16;  // RNE
    return (ushort)r;
}
__device__ __forceinline__ float bflo(uint u) { return __uint_as_float(u << 16); }
__device__ __forceinline__ float bfhi(uint u) { return __uint_as_float(u & 0xffff0000u); }

// ---------------------------------------------------------------------------
// Device-scope grid barrier: generation counter, self-restoring across calls
// (cnt always returns to 0; gen grows monotonically — no per-call init).
// Residency guaranteed by occupancy-sized grid + __launch_bounds__.
// ---------------------------------------------------------------------------
__device__ int g_bar_cnt = 0;
__device__ int g_bar_gen = 0;

__device__ __forceinline__ void grid_barrier() {
    __syncthreads();
    if (threadIdx.x == 0) {
        __threadfence();  // release: flush this XCD's prior writes
        int g = __hip_atomic_load(&g_bar_gen, __ATOMIC_RELAXED, __HIP_MEMORY_SCOPE_AGENT);
        int a = __hip_atomic_fetch_add(&g_bar_cnt, 1, __ATOMIC_ACQ_REL, __HIP_MEMORY_SCOPE_AGENT);
        if (a == (int)gridDim.x - 1) {
            __hip_atomic_store(&g_bar_cnt, 0, __ATOMIC_RELAXED, __HIP_MEMORY_SCOPE_AGENT);
            __hip_atomic_fetch_add(&g_bar_gen, 1, __ATOMIC_RELEASE, __HIP_MEMORY_SCOPE_AGENT);
        } else {
            while (__hip_atomic_load(&g_bar_gen, __ATOMIC_ACQUIRE, __HIP_MEMORY_SCOPE_AGENT) == g)
                __builtin_amdgcn_s_sleep(2);
        }
        __threadfence();  // acquire: invalidate stale local cache
    }
    __syncthreads();
}

// ---------------------------------------------------------------------------
// Gather-side mean for one node (one wave). dwordx4/lane, 16 lanes per row,
// 4 edges per VMEM instruction; fully PREDICATED tail (no duplicate row
// requests — we are request-bound). fp32 accumulate, bf16 store.
// ---------------------------------------------------------------------------
__device__ __forceinline__ void gather_node(
    const ushort* __restrict__ feat, const int* __restrict__ offsets,
    const int* __restrict__ edge_src, ushort* __restrict__ mean,
    int wid, int lane) {
    int beg = offsets[wid];
    int end = offsets[wid + 1];
    int q = lane >> 4;   // which edge of the quad
    int c = lane & 15;   // channel group: bf16 channels c*8 .. c*8+7
    float s0 = 0, s1 = 0, s2 = 0, s3 = 0, s4 = 0, s5 = 0, s6 = 0, s7 = 0;

    int e = beg;
    for (; e + 8 <= end; e += 8) {
        int r0 = edge_src[e + q];
        int r1 = edge_src[e + 4 + q];
        uint4 A = *(const uint4*)(feat + (size_t)r0 * 128 + c * 8);
        uint4 B = *(const uint4*)(feat + (size_t)r1 * 128 + c * 8);
        s0 += bflo(A.x) + bflo(B.x);  s1 += bfhi(A.x) + bfhi(B.x);
        s2 += bflo(A.y) + bflo(B.y);  s3 += bfhi(A.y) + bfhi(B.y);
        s4 += bflo(A.z) + bflo(B.z);  s5 += bfhi(A.z) + bfhi(B.z);
        s6 += bflo(A.w) + bflo(B.w);  s7 += bfhi(A.w) + bfhi(B.w);
    }
    // predicated tail: two 4-edge rounds, no wasted requests
    if (e + q < end) {
        int r0 = edge_src[e + q];
        uint4 A = *(const uint4*)(feat + (size_t)r0 * 128 + c * 8);
        s0 += bflo(A.x);  s1 += bfhi(A.x);
        s2 += bflo(A.y);  s3 += bfhi(A.y);
        s4 += bflo(A.z);  s5 += bfhi(A.z);
        s6 += bflo(A.w);  s7 += bfhi(A.w);
    }
    if (e + 4 + q < end) {
        int r1 = edge_src[e + 4 + q];
        uint4 B = *(const uint4*)(feat + (size_t)r1 * 128 + c * 8);
        s0 += bflo(B.x);  s1 += bfhi(B.x);
        s2 += bflo(B.y);  s3 += bfhi(B.y);
        s4 += bflo(B.z);  s5 += bfhi(B.z);
        s6 += bflo(B.w);  s7 += bfhi(B.w);
    }

    // combine the 4 quarter-wave partials (lanes c, c+16, c+32, c+48)
#pragma unroll
    for (int m = 16; m < 64; m <<= 1) {
        s0 += __shfl_xor(s0, m, 64);
        s1 += __shfl_xor(s1, m, 64);
        s2 += __shfl_xor(s2, m, 64);
        s3 += __shfl_xor(s3, m, 64);
        s4 += __shfl_xor(s4, m, 64);
        s5 += __shfl_xor(s5, m, 64);
        s6 += __shfl_xor(s6, m, 64);
        s7 += __shfl_xor(s7, m, 64);
    }

    if (q == 0) {
        float inv = 1.0f / fmaxf((float)(end - beg), 1.0f);
        uint4 o;
        o.x = (uint)f2bf(s0 * inv) | ((uint)f2bf(s1 * inv) << 16);
        o.y = (uint)f2bf(s2 * inv) | ((uint)f2bf(s3 * inv) << 16);
        o.z = (uint)f2bf(s4 * inv) | ((uint)f2bf(s5 * inv) << 16);
        o.w = (uint)f2bf(s6 * inv) | ((uint)f2bf(s7 * inv) << 16);
        *(uint4*)(mean + (size_t)wid * 128 + c * 8) = o;
    }
}

// ---------------------------------------------------------------------------
// MFMA tiles (verbatim math from the passing r7 kernels, parameterized by m0)
// ---------------------------------------------------------------------------
__device__ __forceinline__ void l1_tile(
    const ushort* __restrict__ mean, const ushort* __restrict__ xb,
    const ushort* __restrict__ WlT, const ushort* __restrict__ WrT,
    const float* __restrict__ b, ushort* __restrict__ h,
    int m0, int lane, int n_nodes) {
    int r  = lane & 15;
    int ko = (lane >> 4) * 8;
    int gc0 = min(m0 + r,      n_nodes - 1);
    int gc1 = min(m0 + 16 + r, n_nodes - 1);

    f32x4 acc[8][2] = {};
#pragma unroll
    for (int kk = 0; kk < 4; ++kk) {
        int kb = kk * 32 + ko;
        bf16x8 aM0 = *(const bf16x8*)(mean + (size_t)gc0 * 128 + kb);
        bf16x8 aM1 = *(const bf16x8*)(mean + (size_t)gc1 * 128 + kb);
        bf16x8 aX0 = *(const bf16x8*)(xb   + (size_t)gc0 * 128 + kb);
        bf16x8 aX1 = *(const bf16x8*)(xb   + (size_t)gc1 * 128 + kb);
#pragma unroll
        for (int j = 0; j < 8; ++j) {
            bf16x8 bL = *(const bf16x8*)(WlT + (size_t)(j * 16 + r) * 128 + kb);
            bf16x8 bR = *(const bf16x8*)(WrT + (size_t)(j * 16 + r) * 128 + kb);
            acc[j][0] = __builtin_amdgcn_mfma_f32_16x16x32_bf16(aM0, bL, acc[j][0], 0, 0, 0);
            acc[j][0] = __builtin_amdgcn_mfma_f32_16x16x32_bf16(aX0, bR, acc[j][0], 0, 0, 0);
            acc[j][1] = __builtin_amdgcn_mfma_f32_16x16x32_bf16(aM1, bL, acc[j][1], 0, 0, 0);
            acc[j][1] = __builtin_amdgcn_mfma_f32_16x16x32_bf16(aX1, bR, acc[j][1], 0, 0, 0);
        }
    }
#pragma unroll
    for (int j = 0; j < 8; ++j) {
        float bv = b[j * 16 + r];
#pragma unroll
        for (int s = 0; s < 2; ++s) {
            int rowbase = m0 + s * 16 + (lane >> 4) * 4;
#pragma unroll
            for (int q2 = 0; q2 < 4; ++q2) {
                int g = rowbase + q2;
                if (g < n_nodes)
                    h[(size_t)g * 128 + j * 16 + r] =
                        f2bf(fmaxf(acc[j][s][q2] + bv, 0.f));
            }
        }
    }
}

__device__ __forceinline__ void l2_tile(
    const ushort* __restrict__ mean, const ushort* __restrict__ hb,
    const ushort* __restrict__ WlT, const ushort* __restrict__ WrT,
    const float* __restrict__ b, float* __restrict__ out,
    int m0, int lane, int n_nodes) {
    int r  = lane & 15;
    int ko = (lane >> 4) * 8;
    int gc0 = min(m0 + r,      n_nodes - 1);
    int gc1 = min(m0 + 16 + r, n_nodes - 1);

    f32x4 acc[4][2] = {};
#pragma unroll
    for (int kk = 0; kk < 4; ++kk) {
        int kb = kk * 32 + ko;
        bf16x8 aM0 = *(const bf16x8*)(mean + (size_t)gc0 * 128 + kb);
        bf16x8 aM1 = *(const bf16x8*)(mean + (size_t)gc1 * 128 + kb);
        bf16x8 aH0 = *(const bf16x8*)(hb   + (size_t)gc0 * 128 + kb);
        bf16x8 aH1 = *(const bf16x8*)(hb   + (size_t)gc1 * 128 + kb);
#pragma unroll
        for (int j = 0; j < 4; ++j) {
            bf16x8 bL = *(const bf16x8*)(WlT + (size_t)(j * 16 + r) * 128 + kb);
            bf16x8 bR = *(const bf16x8*)(WrT + (size_t)(j * 16 + r) * 128 + kb);
            acc[j][0] = __builtin_amdgcn_mfma_f32_16x16x32_bf16(aM0, bL, acc[j][0], 0, 0, 0);
            acc[j][0] = __builtin_amdgcn_mfma_f32_16x16x32_bf16(aH0, bR, acc[j][0], 0, 0, 0);
            acc[j][1] = __builtin_amdgcn_mfma_f32_16x16x32_bf16(aM1, bL, acc[j][1], 0, 0, 0);
            acc[j][1] = __builtin_amdgcn_mfma_f32_16x16x32_bf16(aH1, bR, acc[j][1], 0, 0, 0);
        }
    }
#pragma unroll
    for (int j = 0; j < 4; ++j) {
        float bv = b[j * 16 + r];
#pragma unroll
        for (int s = 0; s < 2; ++s) {
            int rowbase = m0 + s * 16 + (lane >> 4) * 4;
#pragma unroll
            for (int q2 = 0; q2 < 4; ++q2) {
                int g = rowbase + q2;
                if (g < n_nodes)
                    out[(size_t)g * 64 + j * 16 + r] = acc[j][s][q2] + bv;
            }
        }
    }
}

// ---------------------------------------------------------------------------
// Mega kernel: whole pipeline, 8 grid barriers, zero extra dispatches.
// ---------------------------------------------------------------------------
struct Params {
    const int* ei; const float* x;
    const float* W1l; const float* W1r; const float* b1;
    const float* W2l; const float* W2r; const float* b2;
    int* deg; int* offsets; int* cursor; int* partials; int* edge_src;
    ushort* xb; ushort* meanb; ushort* hb;
    ushort* W1lT; ushort* W1rT; ushort* W2lT; ushort* W2rT;
    float* out;
    int n_nodes, n_edges, nsb;
};

__global__ __launch_bounds__(256, 2) void mega_kernel(Params p) {
    int tid  = threadIdx.x;
    int gt   = blockIdx.x * 256 + tid;
    int nthr = gridDim.x * 256;
    int lane = tid & 63;
    int wave = tid >> 6;
    __shared__ int sA[SCAN_B];
    __shared__ int sB[SCAN_B];

    // ---- P0: zero deg, x->bf16, W transposes ----
    for (int i = gt; i < p.n_nodes; i += nthr) p.deg[i] = 0;
    int nx8 = p.n_nodes * 128 / 8;
    for (int i = gt; i < nx8; i += nthr) {
        float4 v0 = *(const float4*)(p.x + (size_t)i * 8);
        float4 v1 = *(const float4*)(p.x + (size_t)i * 8 + 4);
        uint4 o;
        o.x = (uint)f2bf(v0.x) | ((uint)f2bf(v0.y) << 16);
        o.y = (uint)f2bf(v0.z) | ((uint)f2bf(v0.w) << 16);
        o.z = (uint)f2bf(v1.x) | ((uint)f2bf(v1.y) << 16);
        o.w = (uint)f2bf(v1.z) | ((uint)f2bf(v1.w) << 16);
        *(uint4*)(p.xb + (size_t)i * 8) = o;
    }
    for (int t = gt; t < 49152; t += nthr) {
        if (t < 16384)       { int nn = t >> 7, kk = t & 127;            p.W1lT[t] = f2bf(p.W1l[kk * 128 + nn]); }
        else if (t < 32768)  { int u = t - 16384; int nn = u >> 7, kk = u & 127; p.W1rT[u] = f2bf(p.W1r[kk * 128 + nn]); }
        else if (t < 40960)  { int u = t - 32768; int nn = u >> 7, kk = u & 127; p.W2lT[u] = f2bf(p.W2l[kk * 64 + nn]); }
        else                 { int u = t - 40960; int nn = u >> 7, kk = u & 127; p.W2rT[u] = f2bf(p.W2r[kk * 64 + nn]); }
    }
    grid_barrier();

    // ---- P1: degree count ----
    int ne4 = p.n_edges >> 2;
    for (int e4 = gt; e4 < ne4; e4 += nthr) {
        int4 d = *(const int4*)(p.ei + p.n_edges + (size_t)e4 * 4);
        atomicAdd(&p.deg[d.x], 1); atomicAdd(&p.deg[d.y], 1);
        atomicAdd(&p.deg[d.z], 1); atomicAdd(&p.deg[d.w], 1);
    }
    for (int e = ne4 * 4 + gt; e < p.n_edges; e += nthr)
        atomicAdd(&p.deg[p.ei[p.n_edges + e]], 1);
    grid_barrier();

    // ---- P2: per-chunk partial sums ----
    for (int ch = blockIdx.x; ch < p.nsb; ch += gridDim.x) {
        int i = ch * SCAN_B + tid;
        int v = (i < p.n_nodes) ? p.deg[i] : 0;
        for (int m = 32; m > 0; m >>= 1) v += __shfl_down(v, m, 64);
        if (lane == 0) sA[wave] = v;
        __syncthreads();
        if (tid == 0) p.partials[ch] = sA[0] + sA[1] + sA[2] + sA[3];
        __syncthreads();
    }
    grid_barrier();

    // ---- P3: per-chunk scan (redundant base scan of partials in LDS) ----
    for (int ch = blockIdx.x; ch < p.nsb; ch += gridDim.x) {
        sA[tid] = (tid < p.nsb) ? p.partials[tid] : 0;
        __syncthreads();
        for (int m = 1; m < SCAN_B; m <<= 1) {
            int u = (tid >= m) ? sA[tid - m] : 0;
            __syncthreads();
            sA[tid] += u;
            __syncthreads();
        }
        int base  = (ch > 0) ? sA[ch - 1] : 0;
        int total = sA[p.nsb - 1];
        int i = ch * SCAN_B + tid;
        int v = (i < p.n_nodes) ? p.deg[i] : 0;
        sB[tid] = v;
        __syncthreads();
        for (int m = 1; m < SCAN_B; m <<= 1) {
            int u = (tid >= m) ? sB[tid - m] : 0;
            __syncthreads();
            sB[tid] += u;
            __syncthreads();
        }
        if (i < p.n_nodes) {
            int o = base + sB[tid] - v;
            p.offsets[i] = o;
            p.cursor[i]  = o;
        }
        if (ch == p.nsb - 1 && tid == 0) p.offsets[p.n_nodes] = total;
        __syncthreads();
    }
    grid_barrier();

    // ---- P4: CSR fill ----
    for (int e4 = gt; e4 < ne4; e4 += nthr) {
        int4 s = *(const int4*)(p.ei + (size_t)e4 * 4);
        int4 d = *(const int4*)(p.ei + p.n_edges + (size_t)e4 * 4);
        p.edge_src[atomicAdd(&p.cursor[d.x], 1)] = s.x;
        p.edge_src[atomicAdd(&p.cursor[d.y], 1)] = s.y;
        p.edge_src[atomicAdd(&p.cursor[d.z], 1)] = s.z;
        p.edge_src[atomicAdd(&p.cursor[d.w], 1)] = s.w;
    }
    for (int e = ne4 * 4 + gt; e < p.n_edges; e += nthr) {
        int s = p.ei[e], d = p.ei[p.n_edges + e];
        p.edge_src[atomicAdd(&p.cursor[d], 1)] = s;
    }
    grid_barrier();

    // ---- P5: gather1 (x) ----
    int gw = blockIdx.x * 4 + wave, nw = gridDim.x * 4;
    for (int wid = gw; wid < p.n_nodes; wid += nw)
        gather_node(p.xb, p.offsets, p.edge_src, p.meanb, wid, lane);
    grid_barrier();

    // ---- P6: layer-1 MFMA ----
    for (int t0 = blockIdx.x * 128; t0 < p.n_nodes; t0 += gridDim.x * 128)
        l1_tile(p.meanb, p.xb, p.W1lT, p.W1rT, p.b1, p.hb, t0 + wave * 32, lane, p.n_nodes);
    grid_barrier();

    // ---- P7: gather2 (h) ----
    for (int wid = gw; wid < p.n_nodes; wid += nw)
        gather_node(p.hb, p.offsets, p.edge_src, p.meanb, wid, lane);
    grid_barrier();

    // ---- P8: layer-2 MFMA ----
    for (int t0 = blockIdx.x * 128; t0 < p.n_nodes; t0 += gridDim.x * 128)
        l2_tile(p.meanb, p.hb, p.W2lT, p.W2rT, p.b2, p.out, t0 + wave * 32, lane, p.n_nodes);
}

// ---------------------------------------------------------------------------

extern "C" void kernel_launch(void* const* d_in, const int* in_sizes, int n_in,
                              void* d_out, int out_size, void* d_ws, size_t ws_size,
                              hipStream_t stream) {
    Params p;
    p.x   = (const float*)d_in[0];
    p.ei  = (const int*)d_in[1];
    p.W1l = (const float*)d_in[2];
    p.W1r = (const float*)d_in[3];
    p.b1  = (const float*)d_in[4];
    p.W2l = (const float*)d_in[5];
    p.W2r = (const float*)d_in[6];
    p.b2  = (const float*)d_in[7];
    p.out = (float*)d_out;

    p.n_nodes = in_sizes[0] / 128;
    p.n_edges = in_sizes[1] / 2;
    p.nsb = (p.n_nodes + SCAN_B - 1) / SCAN_B;   // must be <= 256 (n <= 65536): 196 here

    // Workspace layout
    char* ws   = (char*)d_ws;
    p.deg      = (int*)ws;                        // n
    p.offsets  = p.deg + p.n_nodes;               // n+1
    p.cursor   = p.offsets + p.n_nodes + 1;       // n
    p.partials = p.cursor + p.n_nodes;            // nsb
    p.edge_src = p.partials + p.nsb;              // E
    size_t off = ((size_t)(3 * p.n_nodes + 1 + p.nsb + p.n_edges)) * sizeof(int);
    off = (off + 255) & ~(size_t)255;
    p.xb    = (ushort*)(ws + off);                    // n*128 bf16
    p.meanb = p.xb    + (size_t)p.n_nodes * 128;      // n*128 bf16
    p.hb    = p.meanb + (size_t)p.n_nodes * 128;      // n*128 bf16
    p.W1lT  = p.hb    + (size_t)p.n_nodes * 128;      // 128*128
    p.W1rT  = p.W1lT + 128 * 128;
    p.W2lT  = p.W1rT + 128 * 128;                     // 64*128
    p.W2rT  = p.W2lT + 64 * 128;

    // Size grid to guaranteed co-residency (hand grid barrier requires it).
    int maxActive = 0;
    (void)hipOccupancyMaxActiveBlocksPerMultiprocessor(&maxActive, mega_kernel, 256, 0);
    if (maxActive < 1) maxActive = 1;
    if (maxActive > 8) maxActive = 8;
    int nCU = 0;
    (void)hipDeviceGetAttribute(&nCU, hipDeviceAttributeMultiprocessorCount, 0);
    if (nCU <= 0) nCU = 256;
    int grid = maxActive * nCU;

    hipLaunchKernelGGL(mega_kernel, dim3(grid), dim3(256), 0, stream, p);
}

// Round 11
// 250.184 us; speedup vs baseline: 3.0025x; 3.0025x over previous
//
#include <hip/hip_runtime.h>
#include <hip/hip_bf16.h>

#define IN_CH 128
#define SCAN_B 256

typedef __attribute__((ext_vector_type(8))) short bf16x8;
typedef __attribute__((ext_vector_type(4))) float f32x4;

__device__ __forceinline__ ushort f2bf(float f) {
    uint u = __float_as_uint(f);
    uint r = (u + 0x7fffu + ((u >> 16) & 1u)) >> 16;  // RNE
    return (ushort)r;
}
__device__ __forceinline__ float bflo(uint u) { return __uint_as_float(u << 16); }
__device__ __forceinline__ float bfhi(uint u) { return __uint_as_float(u & 0xffff0000u); }

// ---------------------------------------------------------------------------
// Fused prep: [count_deg blocks] [x->bf16 blocks] [W transpose blocks]
// ---------------------------------------------------------------------------

__global__ __launch_bounds__(256) void prep_count_kernel(
    const int* __restrict__ ei, int* __restrict__ deg,
    const float* __restrict__ x, ushort* __restrict__ xb,
    const float* __restrict__ W1l, const float* __restrict__ W1r,
    const float* __restrict__ W2l, const float* __restrict__ W2r,
    ushort* __restrict__ W1lT, ushort* __restrict__ W1rT,
    ushort* __restrict__ W2lT, ushort* __restrict__ W2rT,
    int n_edges, int nx, int cnt_blocks, int cvt_blocks) {
    int b = blockIdx.x, tid = threadIdx.x;
    if (b < cnt_blocks) {
        int e4 = b * 256 + tid;
        if (e4 * 4 < n_edges) {
            int4 d = *(const int4*)(ei + n_edges + e4 * 4);  // dst row
            atomicAdd(&deg[d.x], 1);
            atomicAdd(&deg[d.y], 1);
            atomicAdd(&deg[d.z], 1);
            atomicAdd(&deg[d.w], 1);
        }
    } else if (b < cnt_blocks + cvt_blocks) {
        int i = (b - cnt_blocks) * 256 + tid;
        if (i * 8 < nx) {
            float4 v0 = *(const float4*)(x + i * 8);
            float4 v1 = *(const float4*)(x + i * 8 + 4);
            uint4 o;
            o.x = (uint)f2bf(v0.x) | ((uint)f2bf(v0.y) << 16);
            o.y = (uint)f2bf(v0.z) | ((uint)f2bf(v0.w) << 16);
            o.z = (uint)f2bf(v1.x) | ((uint)f2bf(v1.y) << 16);
            o.w = (uint)f2bf(v1.z) | ((uint)f2bf(v1.w) << 16);
            *(uint4*)(xb + i * 8) = o;
        }
    } else {
        int t = (b - cnt_blocks - cvt_blocks) * 256 + tid;
        if (t < 16384) {                       // W1l^T  [128][128]
            int nn = t >> 7, kk = t & 127;
            W1lT[t] = f2bf(W1l[kk * 128 + nn]);
        } else if (t < 32768) {                // W1r^T
            int u = t - 16384;
            int nn = u >> 7, kk = u & 127;
            W1rT[u] = f2bf(W1r[kk * 128 + nn]);
        } else if (t < 40960) {                // W2l^T  [64][128]
            int u = t - 32768;
            int nn = u >> 7, kk = u & 127;
            W2lT[u] = f2bf(W2l[kk * 64 + nn]);
        } else if (t < 49152) {                // W2r^T
            int u = t - 40960;
            int nn = u >> 7, kk = u & 127;
            W2rT[u] = f2bf(W2r[kk * 64 + nn]);
        }
    }
}

// ---------------------------------------------------------------------------
// Scan: per-chunk partial sums, then per-chunk scan with redundant LDS base
// scan of the partials (nsb <= 256), writing offsets & cursor.
// ---------------------------------------------------------------------------

__global__ __launch_bounds__(SCAN_B) void scan_partials_kernel(
    const int* __restrict__ deg, int* __restrict__ partials, int n) {
    __shared__ int ws[SCAN_B / 64];
    int i = blockIdx.x * SCAN_B + threadIdx.x;
    int v = (i < n) ? deg[i] : 0;
    for (int off = 32; off > 0; off >>= 1) v += __shfl_down(v, off, 64);
    int lane = threadIdx.x & 63, w = threadIdx.x >> 6;
    if (lane == 0) ws[w] = v;
    __syncthreads();
    if (threadIdx.x == 0) {
        int s = 0;
        for (int k = 0; k < SCAN_B / 64; ++k) s += ws[k];
        partials[blockIdx.x] = s;
    }
}

__global__ __launch_bounds__(SCAN_B) void scan_final_kernel(
    const int* __restrict__ deg, const int* __restrict__ partials,
    int* __restrict__ offsets, int* __restrict__ cursor, int n, int nsb) {
    __shared__ int sA[SCAN_B];
    __shared__ int sB[SCAN_B];
    int t = threadIdx.x;
    // base scan of partials (redundant per block; nsb <= 256)
    sA[t] = (t < nsb) ? partials[t] : 0;
    __syncthreads();
    for (int m = 1; m < SCAN_B; m <<= 1) {
        int u = (t >= m) ? sA[t - m] : 0;
        __syncthreads();
        sA[t] += u;
        __syncthreads();
    }
    int base  = (blockIdx.x > 0) ? sA[blockIdx.x - 1] : 0;
    int total = sA[nsb - 1];
    // local scan of this chunk's degrees
    int i = blockIdx.x * SCAN_B + t;
    int v = (i < n) ? deg[i] : 0;
    sB[t] = v;
    __syncthreads();
    for (int m = 1; m < SCAN_B; m <<= 1) {
        int u = (t >= m) ? sB[t - m] : 0;
        __syncthreads();
        sB[t] += u;
        __syncthreads();
    }
    if (i < n) {
        int o = base + sB[t] - v;
        offsets[i] = o;
        cursor[i]  = o;
    }
    if (blockIdx.x == 0 && t == 0) offsets[n] = total;
}

__global__ __launch_bounds__(256) void fill_kernel(
    const int* __restrict__ ei, int* __restrict__ cursor,
    int* __restrict__ edge_src, int n_edges) {
    int e4 = blockIdx.x * 256 + threadIdx.x;
    if (e4 * 4 >= n_edges) return;
    int4 s = *(const int4*)(ei + e4 * 4);
    int4 d = *(const int4*)(ei + n_edges + e4 * 4);
    edge_src[atomicAdd(&cursor[d.x], 1)] = s.x;
    edge_src[atomicAdd(&cursor[d.y], 1)] = s.y;
    edge_src[atomicAdd(&cursor[d.z], 1)] = s.z;
    edge_src[atomicAdd(&cursor[d.w], 1)] = s.w;
}

// ---------------------------------------------------------------------------
// Gather-side mean, 128-dim bf16 rows (256B): one wave/node, 16 lanes/row,
// 4 edges per VMEM instruction, predicated tail, quarter-wave reduce.
// ---------------------------------------------------------------------------

__global__ __launch_bounds__(256) void gather_mean128_kernel(
    const ushort* __restrict__ feat, const int* __restrict__ offsets,
    const int* __restrict__ edge_src, ushort* __restrict__ mean, int n_nodes) {
    int wid  = (blockIdx.x * blockDim.x + threadIdx.x) >> 6;
    int lane = threadIdx.x & 63;
    if (wid >= n_nodes) return;
    int beg = offsets[wid];
    int end = offsets[wid + 1];
    int q = lane >> 4;
    int c = lane & 15;
    float s0 = 0, s1 = 0, s2 = 0, s3 = 0, s4 = 0, s5 = 0, s6 = 0, s7 = 0;

    int e = beg;
    for (; e + 8 <= end; e += 8) {
        int r0 = edge_src[e + q];
        int r1 = edge_src[e + 4 + q];
        uint4 A = *(const uint4*)(feat + (size_t)r0 * 128 + c * 8);
        uint4 B = *(const uint4*)(feat + (size_t)r1 * 128 + c * 8);
        s0 += bflo(A.x) + bflo(B.x);  s1 += bfhi(A.x) + bfhi(B.x);
        s2 += bflo(A.y) + bflo(B.y);  s3 += bfhi(A.y) + bfhi(B.y);
        s4 += bflo(A.z) + bflo(B.z);  s5 += bfhi(A.z) + bfhi(B.z);
        s6 += bflo(A.w) + bflo(B.w);  s7 += bfhi(A.w) + bfhi(B.w);
    }
    if (e + q < end) {
        int r0 = edge_src[e + q];
        uint4 A = *(const uint4*)(feat + (size_t)r0 * 128 + c * 8);
        s0 += bflo(A.x);  s1 += bfhi(A.x);
        s2 += bflo(A.y);  s3 += bfhi(A.y);
        s4 += bflo(A.z);  s5 += bfhi(A.z);
        s6 += bflo(A.w);  s7 += bfhi(A.w);
    }
    if (e + 4 + q < end) {
        int r1 = edge_src[e + 4 + q];
        uint4 B = *(const uint4*)(feat + (size_t)r1 * 128 + c * 8);
        s0 += bflo(B.x);  s1 += bfhi(B.x);
        s2 += bflo(B.y);  s3 += bfhi(B.y);
        s4 += bflo(B.z);  s5 += bfhi(B.z);
        s6 += bflo(B.w);  s7 += bfhi(B.w);
    }

#pragma unroll
    for (int m = 16; m < 64; m <<= 1) {
        s0 += __shfl_xor(s0, m, 64);
        s1 += __shfl_xor(s1, m, 64);
        s2 += __shfl_xor(s2, m, 64);
        s3 += __shfl_xor(s3, m, 64);
        s4 += __shfl_xor(s4, m, 64);
        s5 += __shfl_xor(s5, m, 64);
        s6 += __shfl_xor(s6, m, 64);
        s7 += __shfl_xor(s7, m, 64);
    }

    if (q == 0) {
        float inv = 1.0f / fmaxf((float)(end - beg), 1.0f);
        uint4 o;
        o.x = (uint)f2bf(s0 * inv) | ((uint)f2bf(s1 * inv) << 16);
        o.y = (uint)f2bf(s2 * inv) | ((uint)f2bf(s3 * inv) << 16);
        o.z = (uint)f2bf(s4 * inv) | ((uint)f2bf(s5 * inv) << 16);
        o.w = (uint)f2bf(s6 * inv) | ((uint)f2bf(s7 * inv) << 16);
        *(uint4*)(mean + (size_t)wid * 128 + c * 8) = o;
    }
}

// ---------------------------------------------------------------------------
// Gather-side mean, 64-dim bf16 rows (128B): 8 lanes/row -> 8 edges per VMEM
// instruction. Half the requests of the 128-dim gather.
// ---------------------------------------------------------------------------

__global__ __launch_bounds__(256) void gather_mean64_kernel(
    const ushort* __restrict__ feat, const int* __restrict__ offsets,
    const int* __restrict__ edge_src, ushort* __restrict__ mean, int n_nodes) {
    int wid  = (blockIdx.x * blockDim.x + threadIdx.x) >> 6;
    int lane = threadIdx.x & 63;
    if (wid >= n_nodes) return;
    int beg = offsets[wid];
    int end = offsets[wid + 1];
    int q = lane >> 3;   // which edge of the oct (0..7)
    int c = lane & 7;    // channel group: bf16 channels c*8 .. c*8+7
    float s0 = 0, s1 = 0, s2 = 0, s3 = 0, s4 = 0, s5 = 0, s6 = 0, s7 = 0;

    int e = beg;
    for (; e + 16 <= end; e += 16) {
        int r0 = edge_src[e + q];
        int r1 = edge_src[e + 8 + q];
        uint4 A = *(const uint4*)(feat + (size_t)r0 * 64 + c * 8);
        uint4 B = *(const uint4*)(feat + (size_t)r1 * 64 + c * 8);
        s0 += bflo(A.x) + bflo(B.x);  s1 += bfhi(A.x) + bfhi(B.x);
        s2 += bflo(A.y) + bflo(B.y);  s3 += bfhi(A.y) + bfhi(B.y);
        s4 += bflo(A.z) + bflo(B.z);  s5 += bfhi(A.z) + bfhi(B.z);
        s6 += bflo(A.w) + bflo(B.w);  s7 += bfhi(A.w) + bfhi(B.w);
    }
    if (e + q < end) {
        int r0 = edge_src[e + q];
        uint4 A = *(const uint4*)(feat + (size_t)r0 * 64 + c * 8);
        s0 += bflo(A.x);  s1 += bfhi(A.x);
        s2 += bflo(A.y);  s3 += bfhi(A.y);
        s4 += bflo(A.z);  s5 += bfhi(A.z);
        s6 += bflo(A.w);  s7 += bfhi(A.w);
    }
    if (e + 8 + q < end) {
        int r1 = edge_src[e + 8 + q];
        uint4 B = *(const uint4*)(feat + (size_t)r1 * 64 + c * 8);
        s0 += bflo(B.x);  s1 += bfhi(B.x);
        s2 += bflo(B.y);  s3 += bfhi(B.y);
        s4 += bflo(B.z);  s5 += bfhi(B.z);
        s6 += bflo(B.w);  s7 += bfhi(B.w);
    }

#pragma unroll
    for (int m = 8; m < 64; m <<= 1) {
        s0 += __shfl_xor(s0, m, 64);
        s1 += __shfl_xor(s1, m, 64);
        s2 += __shfl_xor(s2, m, 64);
        s3 += __shfl_xor(s3, m, 64);
        s4 += __shfl_xor(s4, m, 64);
        s5 += __shfl_xor(s5, m, 64);
        s6 += __shfl_xor(s6, m, 64);
        s7 += __shfl_xor(s7, m, 64);
    }

    if (q == 0) {
        float inv = 1.0f / fmaxf((float)(end - beg), 1.0f);
        uint4 o;
        o.x = (uint)f2bf(s0 * inv) | ((uint)f2bf(s1 * inv) << 16);
        o.y = (uint)f2bf(s2 * inv) | ((uint)f2bf(s3 * inv) << 16);
        o.z = (uint)f2bf(s4 * inv) | ((uint)f2bf(s5 * inv) << 16);
        o.w = (uint)f2bf(s6 * inv) | ((uint)f2bf(s7 * inv) << 16);
        *(uint4*)(mean + (size_t)wid * 64 + c * 8) = o;
    }
}

// ---------------------------------------------------------------------------
// Layer 1 (MFMA): h = relu(mean @ W1l + x @ W1r + b1), bf16 in/out.
// ---------------------------------------------------------------------------

__global__ __launch_bounds__(256) void l1_mfma_kernel(
    const ushort* __restrict__ mean, const ushort* __restrict__ xb,
    const ushort* __restrict__ WlT, const ushort* __restrict__ WrT,
    const float* __restrict__ b, ushort* __restrict__ h, int n_nodes) {
    int wave = threadIdx.x >> 6, lane = threadIdx.x & 63;
    int m0 = (blockIdx.x * 4 + wave) * 32;
    int r  = lane & 15;
    int ko = (lane >> 4) * 8;

    int gc0 = min(m0 + r,      n_nodes - 1);
    int gc1 = min(m0 + 16 + r, n_nodes - 1);

    f32x4 acc[8][2] = {};
#pragma unroll
    for (int kk = 0; kk < 4; ++kk) {
        int kb = kk * 32 + ko;
        bf16x8 aM0 = *(const bf16x8*)(mean + (size_t)gc0 * 128 + kb);
        bf16x8 aM1 = *(const bf16x8*)(mean + (size_t)gc1 * 128 + kb);
        bf16x8 aX0 = *(const bf16x8*)(xb   + (size_t)gc0 * 128 + kb);
        bf16x8 aX1 = *(const bf16x8*)(xb   + (size_t)gc1 * 128 + kb);
#pragma unroll
        for (int j = 0; j < 8; ++j) {
            bf16x8 bL = *(const bf16x8*)(WlT + (size_t)(j * 16 + r) * 128 + kb);
            bf16x8 bR = *(const bf16x8*)(WrT + (size_t)(j * 16 + r) * 128 + kb);
            acc[j][0] = __builtin_amdgcn_mfma_f32_16x16x32_bf16(aM0, bL, acc[j][0], 0, 0, 0);
            acc[j][0] = __builtin_amdgcn_mfma_f32_16x16x32_bf16(aX0, bR, acc[j][0], 0, 0, 0);
            acc[j][1] = __builtin_amdgcn_mfma_f32_16x16x32_bf16(aM1, bL, acc[j][1], 0, 0, 0);
            acc[j][1] = __builtin_amdgcn_mfma_f32_16x16x32_bf16(aX1, bR, acc[j][1], 0, 0, 0);
        }
    }

#pragma unroll
    for (int j = 0; j < 8; ++j) {
        float bv = b[j * 16 + r];
#pragma unroll
        for (int s = 0; s < 2; ++s) {
            int rowbase = m0 + s * 16 + (lane >> 4) * 4;
#pragma unroll
            for (int q = 0; q < 4; ++q) {
                int g = rowbase + q;
                if (g < n_nodes)
                    h[(size_t)g * 128 + j * 16 + r] =
                        f2bf(fmaxf(acc[j][s][q] + bv, 0.f));
            }
        }
    }
}

// ---------------------------------------------------------------------------
// Layer 2a (MFMA): hp = bf16(h @ W2l)  [n,64]  (projection BEFORE the gather)
// ---------------------------------------------------------------------------

__global__ __launch_bounds__(256) void l2p_mfma_kernel(
    const ushort* __restrict__ hb, const ushort* __restrict__ WlT,
    ushort* __restrict__ hp, int n_nodes) {
    int wave = threadIdx.x >> 6, lane = threadIdx.x & 63;
    int m0 = (blockIdx.x * 4 + wave) * 32;
    int r  = lane & 15;
    int ko = (lane >> 4) * 8;

    int gc0 = min(m0 + r,      n_nodes - 1);
    int gc1 = min(m0 + 16 + r, n_nodes - 1);

    f32x4 acc[4][2] = {};
#pragma unroll
    for (int kk = 0; kk < 4; ++kk) {
        int kb = kk * 32 + ko;
        bf16x8 aH0 = *(const bf16x8*)(hb + (size_t)gc0 * 128 + kb);
        bf16x8 aH1 = *(const bf16x8*)(hb + (size_t)gc1 * 128 + kb);
#pragma unroll
        for (int j = 0; j < 4; ++j) {
            bf16x8 bL = *(const bf16x8*)(WlT + (size_t)(j * 16 + r) * 128 + kb);
            acc[j][0] = __builtin_amdgcn_mfma_f32_16x16x32_bf16(aH0, bL, acc[j][0], 0, 0, 0);
            acc[j][1] = __builtin_amdgcn_mfma_f32_16x16x32_bf16(aH1, bL, acc[j][1], 0, 0, 0);
        }
    }
#pragma unroll
    for (int j = 0; j < 4; ++j) {
#pragma unroll
        for (int s = 0; s < 2; ++s) {
            int rowbase = m0 + s * 16 + (lane >> 4) * 4;
#pragma unroll
            for (int q = 0; q < 4; ++q) {
                int g = rowbase + q;
                if (g < n_nodes)
                    hp[(size_t)g * 64 + j * 16 + r] = f2bf(acc[j][s][q]);
            }
        }
    }
}

// ---------------------------------------------------------------------------
// Layer 2b (MFMA): out = m2 + h @ W2r + b2, fp32 output [n,64].
// m2 = gathered mean of hp (bf16), added in the epilogue.
// ---------------------------------------------------------------------------

__global__ __launch_bounds__(256) void l2r_mfma_kernel(
    const ushort* __restrict__ hb, const ushort* __restrict__ WrT,
    const ushort* __restrict__ m2, const float* __restrict__ b,
    float* __restrict__ out, int n_nodes) {
    int wave = threadIdx.x >> 6, lane = threadIdx.x & 63;
    int m0 = (blockIdx.x * 4 + wave) * 32;
    int r  = lane & 15;
    int ko = (lane >> 4) * 8;

    int gc0 = min(m0 + r,      n_nodes - 1);
    int gc1 = min(m0 + 16 + r, n_nodes - 1);

    f32x4 acc[4][2] = {};
#pragma unroll
    for (int kk = 0; kk < 4; ++kk) {
        int kb = kk * 32 + ko;
        bf16x8 aH0 = *(const bf16x8*)(hb + (size_t)gc0 * 128 + kb);
        bf16x8 aH1 = *(const bf16x8*)(hb + (size_t)gc1 * 128 + kb);
#pragma unroll
        for (int j = 0; j < 4; ++j) {
            bf16x8 bR = *(const bf16x8*)(WrT + (size_t)(j * 16 + r) * 128 + kb);
            acc[j][0] = __builtin_amdgcn_mfma_f32_16x16x32_bf16(aH0, bR, acc[j][0], 0, 0, 0);
            acc[j][1] = __builtin_amdgcn_mfma_f32_16x16x32_bf16(aH1, bR, acc[j][1], 0, 0, 0);
        }
    }
#pragma unroll
    for (int j = 0; j < 4; ++j) {
        float bv = b[j * 16 + r];
#pragma unroll
        for (int s = 0; s < 2; ++s) {
            int rowbase = m0 + s * 16 + (lane >> 4) * 4;
#pragma unroll
            for (int q = 0; q < 4; ++q) {
                int g = rowbase + q;
                if (g < n_nodes) {
                    float mv = __uint_as_float((uint)m2[(size_t)g * 64 + j * 16 + r] << 16);
                    out[(size_t)g * 64 + j * 16 + r] = acc[j][s][q] + bv + mv;
                }
            }
        }
    }
}

// ---------------------------------------------------------------------------

extern "C" void kernel_launch(void* const* d_in, const int* in_sizes, int n_in,
                              void* d_out, int out_size, void* d_ws, size_t ws_size,
                              hipStream_t stream) {
    const float* x   = (const float*)d_in[0];
    const int*   ei  = (const int*)d_in[1];
    const float* W1l = (const float*)d_in[2];
    const float* W1r = (const float*)d_in[3];
    const float* b1  = (const float*)d_in[4];
    const float* W2l = (const float*)d_in[5];
    const float* W2r = (const float*)d_in[6];
    const float* b2  = (const float*)d_in[7];
    float* out = (float*)d_out;

    int n_nodes = in_sizes[0] / IN_CH;
    int n_edges = in_sizes[1] / 2;
    int nsb = (n_nodes + SCAN_B - 1) / SCAN_B;   // 196 (<=256 required)

    // Workspace layout
    char* ws = (char*)d_ws;
    int* deg      = (int*)ws;                    // n
    int* offsets  = deg + n_nodes;               // n+1
    int* cursor   = offsets + n_nodes + 1;       // n
    int* partials = cursor + n_nodes;            // nsb
    int* edge_src = partials + nsb;              // E
    size_t off = ((size_t)(3 * n_nodes + 1 + nsb + n_edges)) * sizeof(int);
    off = (off + 255) & ~(size_t)255;
    ushort* xb    = (ushort*)(ws + off);             // n*128 bf16
    ushort* meanb = xb    + (size_t)n_nodes * 128;   // n*128 bf16 (layer-1 mean)
    ushort* hb    = meanb + (size_t)n_nodes * 128;   // n*128 bf16
    ushort* hp    = hb    + (size_t)n_nodes * 128;   // n*64  bf16 (h @ W2l)
    ushort* m2    = hp    + (size_t)n_nodes * 64;    // n*64  bf16 (mean of hp)
    ushort* W1lT  = m2    + (size_t)n_nodes * 64;    // 128*128
    ushort* W1rT  = W1lT + 128 * 128;
    ushort* W2lT  = W1rT + 128 * 128;                // 64*128
    ushort* W2rT  = W2lT + 64 * 128;

    hipMemsetAsync(deg, 0, n_nodes * sizeof(int), stream);

    const int TB = 256;
    int nx = n_nodes * IN_CH;
    int cnt_blocks = (n_edges / 4 + TB - 1) / TB;
    int cvt_blocks = (nx / 8 + TB - 1) / TB;
    int tr_blocks  = (49152 + TB - 1) / TB;

    prep_count_kernel<<<cnt_blocks + cvt_blocks + tr_blocks, TB, 0, stream>>>(
        ei, deg, x, xb, W1l, W1r, W2l, W2r, W1lT, W1rT, W2lT, W2rT,
        n_edges, nx, cnt_blocks, cvt_blocks);
    scan_partials_kernel<<<nsb, SCAN_B, 0, stream>>>(deg, partials, n_nodes);
    scan_final_kernel<<<nsb, SCAN_B, 0, stream>>>(deg, partials, offsets, cursor,
                                                  n_nodes, nsb);
    fill_kernel<<<cnt_blocks, TB, 0, stream>>>(ei, cursor, edge_src, n_edges);

    int gblocks = (n_nodes * 64 + TB - 1) / TB;      // one wave per node
    int mblocks = (n_nodes + 127) / 128;             // 4 waves x 32 rows

    // Layer 1
    gather_mean128_kernel<<<gblocks, TB, 0, stream>>>(xb, offsets, edge_src, meanb, n_nodes);
    l1_mfma_kernel<<<mblocks, 256, 0, stream>>>(meanb, xb, W1lT, W1rT, b1, hb, n_nodes);

    // Layer 2: project first (hp = h@W2l), gather 64-dim, then fuse the rest
    l2p_mfma_kernel<<<mblocks, 256, 0, stream>>>(hb, W2lT, hp, n_nodes);
    gather_mean64_kernel<<<gblocks, TB, 0, stream>>>(hp, offsets, edge_src, m2, n_nodes);
    l2r_mfma_kernel<<<mblocks, 256, 0, stream>>>(hb, W2rT, m2, b2, out, n_nodes);
}